// Round 1
// baseline (861.148 us; speedup 1.0000x reference)
//
#include <hip/hip_runtime.h>
#include <hip/hip_bf16.h>
#include <stdint.h>

#define T_TOK 16384
#define D_DIM 1024
#define E_NUM 8
#define BM 128
#define BN 128
#define BK 64

typedef __attribute__((ext_vector_type(4))) float f32x4;
typedef __attribute__((ext_vector_type(8))) __bf16 bf16x8;
typedef __attribute__((ext_vector_type(4))) unsigned short u16x4;
typedef const __attribute__((address_space(1))) void* gas_ptr;
typedef __attribute__((address_space(3))) void* las_ptr;

__device__ __forceinline__ unsigned short f2b(float f){
  unsigned int u = __float_as_uint(f);
  u = (u + 0x7FFFu + ((u >> 16) & 1u)) >> 16;   // RNE bf16
  return (unsigned short)u;
}

// ---------------- Kernel 1: convert X -> bf16, router softmax, top-2 -> dense w8 ----------------
__global__ __launch_bounds__(256) void k_router(const float* __restrict__ X,
    const float* __restrict__ Wr, const float* __restrict__ br,
    unsigned short* __restrict__ Xb, float* __restrict__ w8)
{
  const int wv = threadIdx.x >> 6, lane = threadIdx.x & 63;
  const int t = blockIdx.x * 4 + wv;
  const float* x = X + (size_t)t * D_DIM;
  unsigned short* xb = Xb + (size_t)t * D_DIM;
  float acc[E_NUM] = {0.f,0.f,0.f,0.f,0.f,0.f,0.f,0.f};
  #pragma unroll
  for (int c = 0; c < 4; ++c){
    const int d = c * 256 + lane * 4;
    f32x4 xv = *reinterpret_cast<const f32x4*>(x + d);
    u16x4 o;
    o[0]=f2b(xv[0]); o[1]=f2b(xv[1]); o[2]=f2b(xv[2]); o[3]=f2b(xv[3]);
    *reinterpret_cast<u16x4*>(xb + d) = o;
    #pragma unroll
    for (int e = 0; e < E_NUM; ++e){
      f32x4 wv4 = *reinterpret_cast<const f32x4*>(Wr + e * D_DIM + d);
      acc[e] += xv[0]*wv4[0] + xv[1]*wv4[1] + xv[2]*wv4[2] + xv[3]*wv4[3];
    }
  }
  #pragma unroll
  for (int e = 0; e < E_NUM; ++e){
    float v = acc[e];
    #pragma unroll
    for (int off = 32; off >= 1; off >>= 1) v += __shfl_xor(v, off, 64);
    acc[e] = v + br[e];
  }
  float m = acc[0];
  #pragma unroll
  for (int e = 1; e < E_NUM; ++e) m = fmaxf(m, acc[e]);
  float p[E_NUM]; float s = 0.f;
  #pragma unroll
  for (int e = 0; e < E_NUM; ++e){ p[e] = __expf(acc[e] - m); s += p[e]; }
  const float inv = 1.f / s;
  int i1 = 0; float v1 = p[0];
  #pragma unroll
  for (int e = 1; e < E_NUM; ++e) if (p[e] > v1){ v1 = p[e]; i1 = e; }
  int i2 = -1; float v2 = -1.f;
  #pragma unroll
  for (int e = 0; e < E_NUM; ++e) if (e != i1 && p[e] > v2){ v2 = p[e]; i2 = e; }
  if (lane < E_NUM){
    float w = (lane == i1) ? v1 * inv : ((lane == i2) ? v2 * inv : 0.f);
    w8[t * E_NUM + lane] = w;
  }
}

// ---------------- Kernel 2: fp32 -> bf16 weight conversion ----------------
__global__ void k_cvt(const float* __restrict__ in, unsigned short* __restrict__ out, int n4)
{
  int i = blockIdx.x * blockDim.x + threadIdx.x;
  if (i >= n4) return;
  f32x4 v = reinterpret_cast<const f32x4*>(in)[i];
  u16x4 o;
  o[0]=f2b(v[0]); o[1]=f2b(v[1]); o[2]=f2b(v[2]); o[3]=f2b(v[3]);
  reinterpret_cast<u16x4*>(out)[i] = o;
}

// ---------------- shared staging helper: 128x64 bf16 tile via global_load_lds(16B) ----------------
__device__ __forceinline__ void stage_tile(const unsigned short* gsrc,
                                           unsigned short* lds, int wv, int lane)
{
  #pragma unroll
  for (int c = 0; c < 4; ++c){
    const int chunk = c * 4 + wv;                 // 16 chunks of 1KB
    const int off = chunk * 1024 + lane * 16;     // byte offset inside the 16KB tile
    const int row = off >> 7;                     // 128B per row (64 bf16)
    const int colB = off & 127;
    const unsigned short* g = gsrc + (size_t)row * D_DIM + (colB >> 1);
    __builtin_amdgcn_global_load_lds((gas_ptr)(const void*)g,
                                     (las_ptr)(void*)(lds + chunk * 512), 16, 0, 0);
  }
}

// ---------------- Kernel 3: dense-8 expert GEMM with weighted accumulation ----------------
__global__ __launch_bounds__(256) void k_expert(const unsigned short* __restrict__ Xb,
    const unsigned short* __restrict__ Web, const float* __restrict__ be,
    const float* __restrict__ w8, unsigned short* __restrict__ Cb)
{
  __shared__ unsigned short Xs[BM * BK];
  __shared__ unsigned short Ws[BN * BK];
  __shared__ float w8s[BM * E_NUM];
  const int tid = threadIdx.x, wv = tid >> 6, lane = tid & 63;
  const int wm = wv >> 1, wn = wv & 1, lr = lane & 15, lg = lane >> 4;
  const int tm = blockIdx.x, tn = blockIdx.y;

  for (int i = tid; i < BM * E_NUM; i += 256) w8s[i] = w8[tm * BM * E_NUM + i];

  f32x4 oacc[4][4] = {};
  #pragma unroll 1
  for (int e = 0; e < E_NUM; ++e){
    f32x4 yacc[4][4] = {};
    #pragma unroll 1
    for (int kt = 0; kt < D_DIM / BK; ++kt){
      __syncthreads();
      stage_tile(Xb + (size_t)tm * BM * D_DIM + kt * BK, Xs, wv, lane);
      stage_tile(Web + (size_t)e * D_DIM * D_DIM + (size_t)tn * BN * D_DIM + kt * BK, Ws, wv, lane);
      __syncthreads();
      #pragma unroll
      for (int kk = 0; kk < BK; kk += 32){
        bf16x8 af[4], bfq[4];
        #pragma unroll
        for (int fm = 0; fm < 4; ++fm)
          af[fm] = *reinterpret_cast<const bf16x8*>(&Xs[(wm*64 + fm*16 + lr) * BK + kk + lg*8]);
        #pragma unroll
        for (int fn = 0; fn < 4; ++fn)
          bfq[fn] = *reinterpret_cast<const bf16x8*>(&Ws[(wn*64 + fn*16 + lr) * BK + kk + lg*8]);
        #pragma unroll
        for (int fm = 0; fm < 4; ++fm){
          #pragma unroll
          for (int fn = 0; fn < 4; ++fn)
            yacc[fm][fn] = __builtin_amdgcn_mfma_f32_16x16x32_bf16(af[fm], bfq[fn], yacc[fm][fn], 0, 0, 0);
        }
      }
    }
    // weighted accumulate: oacc += w8[t,e] * (yacc + be[e][col])
    float bev[4];
    #pragma unroll
    for (int fn = 0; fn < 4; ++fn)
      bev[fn] = be[e * D_DIM + tn * BN + wn*64 + fn*16 + lr];
    #pragma unroll
    for (int fm = 0; fm < 4; ++fm){
      #pragma unroll
      for (int j = 0; j < 4; ++j){
        const int r = wm*64 + fm*16 + lg*4 + j;
        const float w = w8s[r * E_NUM + e];
        #pragma unroll
        for (int fn = 0; fn < 4; ++fn)
          oacc[fm][fn][j] += w * (yacc[fm][fn][j] + bev[fn]);
      }
    }
  }
  // store combined as bf16
  #pragma unroll
  for (int fm = 0; fm < 4; ++fm){
    #pragma unroll
    for (int j = 0; j < 4; ++j){
      const int r = tm*BM + wm*64 + fm*16 + lg*4 + j;
      #pragma unroll
      for (int fn = 0; fn < 4; ++fn){
        const int cc = tn*BN + wn*64 + fn*16 + lr;
        Cb[(size_t)r * D_DIM + cc] = f2b(oacc[fm][fn][j]);
      }
    }
  }
}

// ---------------- Kernel 4: output projection GEMM + bo ----------------
__global__ __launch_bounds__(256) void k_outproj(const unsigned short* __restrict__ Cb,
    const unsigned short* __restrict__ Wob, const float* __restrict__ bo,
    float* __restrict__ out)
{
  __shared__ unsigned short As[BM * BK];
  __shared__ unsigned short Bs[BN * BK];
  const int tid = threadIdx.x, wv = tid >> 6, lane = tid & 63;
  const int wm = wv >> 1, wn = wv & 1, lr = lane & 15, lg = lane >> 4;
  const int tm = blockIdx.x, tn = blockIdx.y;

  f32x4 acc[4][4] = {};
  #pragma unroll 1
  for (int kt = 0; kt < D_DIM / BK; ++kt){
    __syncthreads();
    stage_tile(Cb + (size_t)tm * BM * D_DIM + kt * BK, As, wv, lane);
    stage_tile(Wob + (size_t)tn * BN * D_DIM + kt * BK, Bs, wv, lane);
    __syncthreads();
    #pragma unroll
    for (int kk = 0; kk < BK; kk += 32){
      bf16x8 af[4], bfq[4];
      #pragma unroll
      for (int fm = 0; fm < 4; ++fm)
        af[fm] = *reinterpret_cast<const bf16x8*>(&As[(wm*64 + fm*16 + lr) * BK + kk + lg*8]);
      #pragma unroll
      for (int fn = 0; fn < 4; ++fn)
        bfq[fn] = *reinterpret_cast<const bf16x8*>(&Bs[(wn*64 + fn*16 + lr) * BK + kk + lg*8]);
      #pragma unroll
      for (int fm = 0; fm < 4; ++fm){
        #pragma unroll
        for (int fn = 0; fn < 4; ++fn)
          acc[fm][fn] = __builtin_amdgcn_mfma_f32_16x16x32_bf16(af[fm], bfq[fn], acc[fm][fn], 0, 0, 0);
      }
    }
  }
  float bov[4];
  #pragma unroll
  for (int fn = 0; fn < 4; ++fn)
    bov[fn] = bo[tn * BN + wn*64 + fn*16 + lr];
  #pragma unroll
  for (int fm = 0; fm < 4; ++fm){
    #pragma unroll
    for (int j = 0; j < 4; ++j){
      const int r = tm*BM + wm*64 + fm*16 + lg*4 + j;
      #pragma unroll
      for (int fn = 0; fn < 4; ++fn){
        const int cc = tn*BN + wn*64 + fn*16 + lr;
        out[(size_t)r * D_DIM + cc] = acc[fm][fn][j] + bov[fn];
      }
    }
  }
}

extern "C" void kernel_launch(void* const* d_in, const int* in_sizes, int n_in,
                              void* d_out, int out_size, void* d_ws, size_t ws_size,
                              hipStream_t stream)
{
  const float* X  = (const float*)d_in[0];   // [8,2048,1024]
  const float* We = (const float*)d_in[1];   // [8,1024,1024]
  const float* be = (const float*)d_in[2];   // [8,1024]
  const float* Wr = (const float*)d_in[3];   // [8,1024]
  const float* br = (const float*)d_in[4];   // [8]
  const float* Wo = (const float*)d_in[5];   // [1024,1024]
  const float* bo = (const float*)d_in[6];   // [1024]
  float* out = (float*)d_out;

  char* ws = (char*)d_ws;
  unsigned short* Web = (unsigned short*)(ws);                  // 33,554,432 B
  unsigned short* Wob = (unsigned short*)(ws + 33554432);       //  2,097,152 B
  unsigned short* Cb  = (unsigned short*)(ws + 35651584);       // 33,554,432 B
  float*          w8  = (float*)(ws + 69206016);                //    524,288 B
  unsigned short* Xb  = (unsigned short*)d_out;                 // reuse d_out (dead before k_outproj)

  k_router<<<T_TOK / 4, 256, 0, stream>>>(X, Wr, br, Xb, w8);
  k_cvt<<<(E_NUM * D_DIM * D_DIM / 4) / 256, 256, 0, stream>>>(We, Web, E_NUM * D_DIM * D_DIM / 4);
  k_cvt<<<(D_DIM * D_DIM / 4) / 256, 256, 0, stream>>>(Wo, Wob, D_DIM * D_DIM / 4);

  dim3 gg(T_TOK / BM, D_DIM / BN);
  k_expert<<<gg, 256, 0, stream>>>(Xb, Web, be, w8, Cb);
  k_outproj<<<gg, 256, 0, stream>>>(Cb, Wob, bo, out);
}

// Round 3
// 415.389 us; speedup vs baseline: 2.0731x; 2.0731x over previous
//
#include <hip/hip_runtime.h>
#include <stdint.h>

#define T_TOK 16384
#define D_DIM 1024
#define E_NUM 8
#define NTILE 264          // fixed tile slots: ceil-sum bound 263, padded

typedef __attribute__((ext_vector_type(4))) float f32x4;
typedef __attribute__((ext_vector_type(8))) __bf16 bf16x8;
typedef __attribute__((ext_vector_type(4))) unsigned short u16x4;
typedef __attribute__((ext_vector_type(8))) unsigned short u16x8;
typedef const __attribute__((address_space(1))) void* gas_ptr;
typedef __attribute__((address_space(3))) void* las_ptr;

// ---- ws layout (total ~67.79 MB; ws_size >= 69.73 MB proven in round 1) ----
#define WS_Y     0ULL                      // bf16 Y[32768][1024]
#define WS_ATOK  67108864ULL               // int[32768]
#define WS_AW    (WS_ATOK + 131072ULL)     // float[32768]
#define WS_ROF   (WS_AW + 131072ULL)       // int[32768]
#define WS_TKI   (WS_ROF + 131072ULL)      // int[2*16384]
#define WS_TKW   (WS_TKI + 131072ULL)      // float[2*16384]
#define WS_CNTS  (WS_TKW + 131072ULL)      // int[256*8]
#define WS_BASE  (WS_CNTS + 8192ULL)       // int[256*8]
#define WS_SCHED (WS_BASE + 8192ULL)       // int4[264]

// ---- d_out layout during compute (fully overwritten by k_outproj at the end) ----
// Xb  bf16[16384][1024] at +0          (33,554,432 B)
// Web bf16[8][1024][1024] at +33554432 (16,777,216 B)

__device__ __forceinline__ unsigned short f2b(float f){
  unsigned int u = __float_as_uint(f);
  u = (u + 0x7FFFu + ((u >> 16) & 1u)) >> 16;   // RNE bf16
  return (unsigned short)u;
}
__device__ __forceinline__ float b2f(unsigned short u){
  return __uint_as_float(((unsigned int)u) << 16);
}

// ---------------- router: X->bf16 + logits -> top2 (by logits; softmax weights) ----------------
__global__ __launch_bounds__(256) void k_router(const float* __restrict__ X,
    const float* __restrict__ Wr, const float* __restrict__ br,
    unsigned short* __restrict__ Xb, int* __restrict__ tki, float* __restrict__ tkw)
{
  const int wv = threadIdx.x >> 6, lane = threadIdx.x & 63;
  const int t = blockIdx.x * 4 + wv;
  const float* x = X + (size_t)t * D_DIM;
  unsigned short* xb = Xb + (size_t)t * D_DIM;
  float acc[E_NUM] = {};
  #pragma unroll
  for (int c = 0; c < 4; ++c){
    const int d = c * 256 + lane * 4;
    f32x4 xv = *reinterpret_cast<const f32x4*>(x + d);
    u16x4 o;
    o[0]=f2b(xv[0]); o[1]=f2b(xv[1]); o[2]=f2b(xv[2]); o[3]=f2b(xv[3]);
    *reinterpret_cast<u16x4*>(xb + d) = o;
    #pragma unroll
    for (int e = 0; e < E_NUM; ++e){
      f32x4 w4 = *reinterpret_cast<const f32x4*>(Wr + e * D_DIM + d);
      acc[e] += xv[0]*w4[0] + xv[1]*w4[1] + xv[2]*w4[2] + xv[3]*w4[3];
    }
  }
  #pragma unroll
  for (int e = 0; e < E_NUM; ++e){
    float v = acc[e];
    #pragma unroll
    for (int off = 32; off >= 1; off >>= 1) v += __shfl_xor(v, off, 64);
    acc[e] = v + br[e];
  }
  // top-2 by logits (exp is monotone -> same order as softmax, ties by lower index)
  int i1 = 0; float l1 = acc[0];
  #pragma unroll
  for (int e = 1; e < E_NUM; ++e) if (acc[e] > l1){ l1 = acc[e]; i1 = e; }
  int i2 = -1; float l2 = -3.4e38f;
  #pragma unroll
  for (int e = 0; e < E_NUM; ++e) if (e != i1 && acc[e] > l2){ l2 = acc[e]; i2 = e; }
  float m = l1, s = 0.f;
  float p1 = 0.f, p2 = 0.f;
  #pragma unroll
  for (int e = 0; e < E_NUM; ++e){ float pe = __expf(acc[e] - m); s += pe; }
  p1 = __expf(l1 - m) / s; p2 = __expf(l2 - m) / s;
  if (lane == 0){
    tki[2*t] = i1; tki[2*t+1] = i2;
    tkw[2*t] = p1; tkw[2*t+1] = p2;
  }
}

// ---------------- We f32 -> bf16 ----------------
__global__ void k_cvt(const float* __restrict__ in, unsigned short* __restrict__ out, int n4)
{
  int i = blockIdx.x * blockDim.x + threadIdx.x;
  if (i >= n4) return;
  f32x4 v = reinterpret_cast<const f32x4*>(in)[i];
  u16x4 o;
  o[0]=f2b(v[0]); o[1]=f2b(v[1]); o[2]=f2b(v[2]); o[3]=f2b(v[3]);
  reinterpret_cast<u16x4*>(out)[i] = o;
}

// ---------------- hist: per-64-token-block per-expert counts (ballot, no atomics) ----------------
__global__ __launch_bounds__(64) void k_hist(const int* __restrict__ tki, int* __restrict__ cnts)
{
  const int b = blockIdx.x, lane = threadIdx.x;
  const int t = b * 64 + lane;
  const int e0 = tki[2*t], e1 = tki[2*t+1];
  #pragma unroll
  for (int ex = 0; ex < E_NUM; ++ex){
    unsigned long long m0 = __ballot(e0 == ex);
    unsigned long long m1 = __ballot(e1 == ex);
    if (lane == 0) cnts[b * E_NUM + ex] = __popcll(m0) + __popcll(m1);
  }
}

// ---------------- scan: 1 wave; bases per (block,expert), offs, fixed 264-slot sched ----------------
__global__ __launch_bounds__(64) void k_scan(const int* __restrict__ cnts,
    int* __restrict__ bases, int4* __restrict__ sched)
{
  const int lane = threadIdx.x;        // lane = g*8 + e ; 8 groups x 32 blocks
  const int e = lane & 7, g = lane >> 3;
  int own = 0;
  for (int i = 0; i < 32; ++i) own += cnts[(g * 32 + i) * E_NUM + e];
  int incl = own;
  #pragma unroll
  for (int s = 8; s < 64; s <<= 1){
    int v = __shfl_up(incl, s, 64);
    if (lane >= s) incl += v;
  }
  int tot[E_NUM];
  #pragma unroll
  for (int ee = 0; ee < E_NUM; ++ee) tot[ee] = __shfl(incl, 56 + ee, 64);
  int offs_e = 0;
  #pragma unroll
  for (int ee = 0; ee < E_NUM; ++ee) if (ee < e) offs_e += tot[ee];
  int run = offs_e + (incl - own);
  for (int i = 0; i < 32; ++i){
    const int b = g * 32 + i;
    bases[b * E_NUM + e] = run;
    run += cnts[b * E_NUM + e];
  }
  if (lane == 0){
    int slot = 0, off = 0;
    for (int ee = 0; ee < E_NUM; ++ee){
      const int c = tot[ee];
      for (int tile = 0; tile * 128 < c && slot < NTILE; ++tile)
        sched[slot++] = make_int4(ee, off + tile * 128, min(128, c - tile * 128), 0);
      off += c;
    }
    while (slot < NTILE) sched[slot++] = make_int4(0, 0, 0, 0);
  }
}

// ---------------- scatter: deterministic ballot ranks ----------------
__global__ __launch_bounds__(64) void k_scatter(const int* __restrict__ tki,
    const float* __restrict__ tkw, const int* __restrict__ bases,
    int* __restrict__ atok, float* __restrict__ aw, int* __restrict__ rof)
{
  const int b = blockIdx.x, lane = threadIdx.x;
  const int t = b * 64 + lane;
  const unsigned long long lt = (1ull << lane) - 1ull;
  const int e0 = tki[2*t], e1 = tki[2*t+1];
  int r0 = 0, r1 = 0, p0c[E_NUM];
  #pragma unroll
  for (int ex = 0; ex < E_NUM; ++ex){
    unsigned long long m0 = __ballot(e0 == ex);
    p0c[ex] = __popcll(m0);
    if (e0 == ex) r0 = __popcll(m0 & lt);
  }
  #pragma unroll
  for (int ex = 0; ex < E_NUM; ++ex){
    unsigned long long m1 = __ballot(e1 == ex);
    if (e1 == ex) r1 = p0c[ex] + __popcll(m1 & lt);
  }
  const int row0 = bases[b * E_NUM + e0] + r0;
  const int row1 = bases[b * E_NUM + e1] + r1;
  atok[row0] = t; aw[row0] = tkw[2*t];   rof[2*t]   = row0;
  atok[row1] = t; aw[row1] = tkw[2*t+1]; rof[2*t+1] = row1;
}

// ---------------- expert gather-GEMM: Y[row] = bf16( w * (X[tok] @ We[e]^T + be[e]) ) ----------------
__global__ __launch_bounds__(256) void k_expert(const unsigned short* __restrict__ Xb,
    const unsigned short* __restrict__ Web, const float* __restrict__ be,
    const int4* __restrict__ sched, const int* __restrict__ atok,
    const float* __restrict__ aw, unsigned short* __restrict__ Y)
{
  __shared__ unsigned short As[128 * 64];
  __shared__ unsigned short Bs[128 * 64];
  __shared__ int   tok_s[128];
  __shared__ float w_s[128];

  // lin -> (tile j, n-chunk c): tile's 8 chunks share an XCD; same-expert tiles cluster per XCD
  const int lin = blockIdx.x;             // [0, 2112)
  const int x = lin & 7, c = (lin >> 3) & 7, a = lin >> 6;   // a in [0,33)
  const int j = x * 33 + a;
  const int4 sc = sched[j];
  const int e = sc.x, row0 = sc.y, nval = sc.z;
  const int n0 = c * 128;

  const int tid = threadIdx.x, wv = tid >> 6, lane = tid & 63;
  const int wm = wv >> 1, wn = wv & 1, lr = lane & 15, lg = lane >> 4;

  if (tid < 128){
    tok_s[tid] = atok[row0 + max(0, min(tid, nval - 1))];
    w_s[tid]   = aw[row0 + min(tid, 127)];           // tail garbage guarded below
  }
  __syncthreads();

  // per-lane pre-swizzled sources, wave-uniform LDS dests (m173 pattern)
  const char* asrc[4]; const char* bsrc[4]; int ldso[4];
  #pragma unroll
  for (int i = 0; i < 4; ++i){
    const int chunk = i * 4 + wv;                 // 16 x 1KB
    const int byte0 = chunk * 1024 + lane * 16;
    const int r = byte0 >> 7;                     // tile row
    const int cb = byte0 & 127;
    const int scb = cb ^ ((r & 7) << 4);          // pre-swizzled source col-byte
    asrc[i] = (const char*)(Xb + (size_t)tok_s[r] * D_DIM) + scb;
    bsrc[i] = (const char*)(Web + ((size_t)e * D_DIM + n0 + r) * D_DIM) + scb;
    ldso[i] = chunk * 512;                        // shorts
  }

  f32x4 acc[4][4] = {};
  #pragma unroll 1
  for (int kt = 0; kt < 16; ++kt){
    __syncthreads();
    #pragma unroll
    for (int i = 0; i < 4; ++i){
      __builtin_amdgcn_global_load_lds((gas_ptr)(asrc[i] + kt * 128), (las_ptr)(As + ldso[i]), 16, 0, 0);
      __builtin_amdgcn_global_load_lds((gas_ptr)(bsrc[i] + kt * 128), (las_ptr)(Bs + ldso[i]), 16, 0, 0);
    }
    __syncthreads();
    #pragma unroll
    for (int kk = 0; kk < 2; ++kk){
      bf16x8 af[4], bfr[4];
      #pragma unroll
      for (int fm = 0; fm < 4; ++fm){
        const int r = wm*64 + fm*16 + lr;
        af[fm] = *reinterpret_cast<const bf16x8*>((char*)As + ((r*128 + kk*64 + lg*16) ^ ((r & 7) << 4)));
      }
      #pragma unroll
      for (int fn = 0; fn < 4; ++fn){
        const int r = wn*64 + fn*16 + lr;
        bfr[fn] = *reinterpret_cast<const bf16x8*>((char*)Bs + ((r*128 + kk*64 + lg*16) ^ ((r & 7) << 4)));
      }
      #pragma unroll
      for (int fm = 0; fm < 4; ++fm)
        #pragma unroll
        for (int fn = 0; fn < 4; ++fn)
          acc[fm][fn] = __builtin_amdgcn_mfma_f32_16x16x32_bf16(af[fm], bfr[fn], acc[fm][fn], 0, 0, 0);
    }
  }

  float bev[4];
  #pragma unroll
  for (int fn = 0; fn < 4; ++fn) bev[fn] = be[e * D_DIM + n0 + wn*64 + fn*16 + lr];
  #pragma unroll
  for (int fm = 0; fm < 4; ++fm){
    #pragma unroll
    for (int jj = 0; jj < 4; ++jj){
      const int r = wm*64 + fm*16 + lg*4 + jj;
      if (r < nval){
        const float w = w_s[r];
        #pragma unroll
        for (int fn = 0; fn < 4; ++fn){
          const int col = n0 + wn*64 + fn*16 + lr;
          Y[(size_t)(row0 + r) * D_DIM + col] = f2b(w * (acc[fm][fn][jj] + bev[fn]));
        }
      }
    }
  }
}

// ---------------- out-proj: out = (Y[r0]+Y[r1]) @ Wo^T + bo ----------------
__global__ __launch_bounds__(256) void k_outproj(const unsigned short* __restrict__ Y,
    const float* __restrict__ Wo, const int* __restrict__ rof,
    const float* __restrict__ bo, float* __restrict__ out)
{
  __shared__ unsigned short As[128 * 64];
  __shared__ unsigned short Bs[128 * 64];
  __shared__ int ra_s[128], rb_s[128];

  const int lin = blockIdx.x;             // [0, 1024)
  const int x = lin & 7, c = (lin >> 3) & 7, a = lin >> 6;   // a in [0,16)
  const int tm = x * 16 + a;
  const int n0 = c * 128;

  const int tid = threadIdx.x, wv = tid >> 6, lane = tid & 63;
  const int wm = wv >> 1, wn = wv & 1, lr = lane & 15, lg = lane >> 4;

  if (tid < 128){
    const int t = tm * 128 + tid;
    ra_s[tid] = rof[2*t]; rb_s[tid] = rof[2*t+1];
  }
  __syncthreads();

  const int srow = tid >> 3, scol = (tid & 7) * 8;   // elements (shorts for Y, floats for Wo)
  const unsigned short* ya[4]; const unsigned short* yb[4]; const float* wo[4];
  #pragma unroll
  for (int p = 0; p < 4; ++p){
    const int r = p * 32 + srow;
    ya[p] = Y + (size_t)ra_s[r] * D_DIM + scol;
    yb[p] = Y + (size_t)rb_s[r] * D_DIM + scol;
    wo[p] = Wo + (size_t)(n0 + r) * D_DIM + scol;
  }

  f32x4 acc[4][4] = {};
  #pragma unroll 1
  for (int kt = 0; kt < 16; ++kt){
    __syncthreads();
    #pragma unroll
    for (int p = 0; p < 4; ++p){
      const int r = p * 32 + srow;
      const int ba = (r * 128 + scol * 2) ^ ((r & 7) << 4);
      u16x8 va = *reinterpret_cast<const u16x8*>(ya[p] + kt * 64);
      u16x8 vb = *reinterpret_cast<const u16x8*>(yb[p] + kt * 64);
      u16x8 o;
      #pragma unroll
      for (int i = 0; i < 8; ++i) o[i] = f2b(b2f(va[i]) + b2f(vb[i]));
      *reinterpret_cast<u16x8*>((char*)As + ba) = o;
      f32x4 b0 = *reinterpret_cast<const f32x4*>(wo[p] + kt * 64);
      f32x4 b1 = *reinterpret_cast<const f32x4*>(wo[p] + kt * 64 + 4);
      u16x8 ob;
      ob[0]=f2b(b0[0]); ob[1]=f2b(b0[1]); ob[2]=f2b(b0[2]); ob[3]=f2b(b0[3]);
      ob[4]=f2b(b1[0]); ob[5]=f2b(b1[1]); ob[6]=f2b(b1[2]); ob[7]=f2b(b1[3]);
      *reinterpret_cast<u16x8*>((char*)Bs + ba) = ob;
    }
    __syncthreads();
    #pragma unroll
    for (int kk = 0; kk < 2; ++kk){
      bf16x8 af[4], bfr[4];
      #pragma unroll
      for (int fm = 0; fm < 4; ++fm){
        const int r = wm*64 + fm*16 + lr;
        af[fm] = *reinterpret_cast<const bf16x8*>((char*)As + ((r*128 + kk*64 + lg*16) ^ ((r & 7) << 4)));
      }
      #pragma unroll
      for (int fn = 0; fn < 4; ++fn){
        const int r = wn*64 + fn*16 + lr;
        bfr[fn] = *reinterpret_cast<const bf16x8*>((char*)Bs + ((r*128 + kk*64 + lg*16) ^ ((r & 7) << 4)));
      }
      #pragma unroll
      for (int fm = 0; fm < 4; ++fm)
        #pragma unroll
        for (int fn = 0; fn < 4; ++fn)
          acc[fm][fn] = __builtin_amdgcn_mfma_f32_16x16x32_bf16(af[fm], bfr[fn], acc[fm][fn], 0, 0, 0);
    }
  }

  float bov[4];
  #pragma unroll
  for (int fn = 0; fn < 4; ++fn) bov[fn] = bo[n0 + wn*64 + fn*16 + lr];
  #pragma unroll
  for (int fm = 0; fm < 4; ++fm){
    #pragma unroll
    for (int jj = 0; jj < 4; ++jj){
      const int r = wm*64 + fm*16 + lg*4 + jj;
      #pragma unroll
      for (int fn = 0; fn < 4; ++fn){
        const int col = n0 + wn*64 + fn*16 + lr;
        out[(size_t)(tm * 128 + r) * D_DIM + col] = acc[fm][fn][jj] + bov[fn];
      }
    }
  }
}

extern "C" void kernel_launch(void* const* d_in, const int* in_sizes, int n_in,
                              void* d_out, int out_size, void* d_ws, size_t ws_size,
                              hipStream_t stream)
{
  const float* X  = (const float*)d_in[0];
  const float* We = (const float*)d_in[1];
  const float* be = (const float*)d_in[2];
  const float* Wr = (const float*)d_in[3];
  const float* br = (const float*)d_in[4];
  const float* Wo = (const float*)d_in[5];
  const float* bo = (const float*)d_in[6];
  float* out = (float*)d_out;
  char* ws = (char*)d_ws;

  unsigned short* Y   = (unsigned short*)(ws + WS_Y);
  int*   atok  = (int*)(ws + WS_ATOK);
  float* aw    = (float*)(ws + WS_AW);
  int*   rof   = (int*)(ws + WS_ROF);
  int*   tki   = (int*)(ws + WS_TKI);
  float* tkw   = (float*)(ws + WS_TKW);
  int*   cnts  = (int*)(ws + WS_CNTS);
  int*   bases = (int*)(ws + WS_BASE);
  int4*  sched = (int4*)(ws + WS_SCHED);

  unsigned short* Xb  = (unsigned short*)d_out;                       // 33.5 MB
  unsigned short* Web = (unsigned short*)((char*)d_out + 33554432);   // 16.8 MB (both dead before out write)

  k_router<<<T_TOK / 4, 256, 0, stream>>>(X, Wr, br, Xb, tki, tkw);
  k_cvt<<<(E_NUM * D_DIM * D_DIM / 4) / 256, 256, 0, stream>>>(We, Web, E_NUM * D_DIM * D_DIM / 4);
  k_hist<<<256, 64, 0, stream>>>(tki, cnts);
  k_scan<<<1, 64, 0, stream>>>(cnts, bases, sched);
  k_scatter<<<256, 64, 0, stream>>>(tki, tkw, bases, atok, aw, rof);
  k_expert<<<NTILE * 8, 256, 0, stream>>>(Xb, Web, be, sched, atok, aw, Y);
  k_outproj<<<1024, 256, 0, stream>>>(Y, Wo, rof, bo, out);
}

// Round 4
// 352.501 us; speedup vs baseline: 2.4430x; 1.1784x over previous
//
#include <hip/hip_runtime.h>
#include <stdint.h>

#define T_TOK 16384
#define D_DIM 1024
#define E_NUM 8
#define NTILE 264          // fixed tile slots: ceil-sum bound 263, padded

typedef __attribute__((ext_vector_type(4))) float f32x4;
typedef __attribute__((ext_vector_type(8))) __bf16 bf16x8;
typedef __attribute__((ext_vector_type(4))) unsigned short u16x4;
typedef const __attribute__((address_space(1))) void* gas_ptr;
typedef __attribute__((address_space(3))) void* las_ptr;

// ---- ws layout (ws_size >= 69,730,304 proven in round 1) ----
#define WS_Y     0ULL                      // bf16 Y[32768][1024] = 67,108,864
#define WS_ATOK  67108864ULL               // int[32768]  (value = 2*token + k)
#define WS_AW    (WS_ATOK + 131072ULL)     // float[32768]
#define WS_SCHED (WS_AW + 131072ULL)       // int4[264], padded region 8192
#define WS_TMP   (WS_SCHED + 8192ULL)      // scratch region, dead after k_scatter
#define WS_TKI   WS_TMP                    // int[2*16384]
#define WS_TKW   (WS_TKI + 131072ULL)      // float[2*16384]
#define WS_CNTS  (WS_TKW + 131072ULL)      // int[256*8]
#define WS_BASE  (WS_CNTS + 8192ULL)       // int[256*8]   (ends 67,657,728)
#define WS_WOB   WS_TMP                    // bf16[1024][1024] = 2,097,152 (overlaps TKI.., written after scatter; ends 69,476,352)

// ---- d_out layout during compute (fully overwritten by k_outproj at the end) ----
// Xb  bf16[16384][1024] at +0          (33,554,432 B)
// Web bf16[8][1024][1024] at +33554432 (16,777,216 B)

__device__ __forceinline__ unsigned short f2b(float f){
  unsigned int u = __float_as_uint(f);
  u = (u + 0x7FFFu + ((u >> 16) & 1u)) >> 16;   // RNE bf16
  return (unsigned short)u;
}

// ---------------- router: X->bf16 + logits -> top2 (by logits; softmax weights) ----------------
__global__ __launch_bounds__(256) void k_router(const float* __restrict__ X,
    const float* __restrict__ Wr, const float* __restrict__ br,
    unsigned short* __restrict__ Xb, int* __restrict__ tki, float* __restrict__ tkw)
{
  const int wv = threadIdx.x >> 6, lane = threadIdx.x & 63;
  const int t = blockIdx.x * 4 + wv;
  const float* x = X + (size_t)t * D_DIM;
  unsigned short* xb = Xb + (size_t)t * D_DIM;
  float acc[E_NUM] = {};
  #pragma unroll
  for (int c = 0; c < 4; ++c){
    const int d = c * 256 + lane * 4;
    f32x4 xv = *reinterpret_cast<const f32x4*>(x + d);
    u16x4 o;
    o[0]=f2b(xv[0]); o[1]=f2b(xv[1]); o[2]=f2b(xv[2]); o[3]=f2b(xv[3]);
    *reinterpret_cast<u16x4*>(xb + d) = o;
    #pragma unroll
    for (int e = 0; e < E_NUM; ++e){
      f32x4 w4 = *reinterpret_cast<const f32x4*>(Wr + e * D_DIM + d);
      acc[e] += xv[0]*w4[0] + xv[1]*w4[1] + xv[2]*w4[2] + xv[3]*w4[3];
    }
  }
  #pragma unroll
  for (int e = 0; e < E_NUM; ++e){
    float v = acc[e];
    #pragma unroll
    for (int off = 32; off >= 1; off >>= 1) v += __shfl_xor(v, off, 64);
    acc[e] = v + br[e];
  }
  int i1 = 0; float l1 = acc[0];
  #pragma unroll
  for (int e = 1; e < E_NUM; ++e) if (acc[e] > l1){ l1 = acc[e]; i1 = e; }
  int i2 = -1; float l2 = -3.4e38f;
  #pragma unroll
  for (int e = 0; e < E_NUM; ++e) if (e != i1 && acc[e] > l2){ l2 = acc[e]; i2 = e; }
  float s = 0.f;
  #pragma unroll
  for (int e = 0; e < E_NUM; ++e) s += __expf(acc[e] - l1);
  if (lane == 0){
    tki[2*t] = i1; tki[2*t+1] = i2;
    tkw[2*t] = __expf(l1 - l1) / s; tkw[2*t+1] = __expf(l2 - l1) / s;
  }
}

// ---------------- f32 -> bf16 conversion ----------------
__global__ void k_cvt(const float* __restrict__ in, unsigned short* __restrict__ out, int n4)
{
  int i = blockIdx.x * blockDim.x + threadIdx.x;
  if (i >= n4) return;
  f32x4 v = reinterpret_cast<const f32x4*>(in)[i];
  u16x4 o;
  o[0]=f2b(v[0]); o[1]=f2b(v[1]); o[2]=f2b(v[2]); o[3]=f2b(v[3]);
  reinterpret_cast<u16x4*>(out)[i] = o;
}

// ---------------- hist: per-64-token-block per-expert counts (ballot, no atomics) ----------------
__global__ __launch_bounds__(64) void k_hist(const int* __restrict__ tki, int* __restrict__ cnts)
{
  const int b = blockIdx.x, lane = threadIdx.x;
  const int t = b * 64 + lane;
  const int e0 = tki[2*t], e1 = tki[2*t+1];
  #pragma unroll
  for (int ex = 0; ex < E_NUM; ++ex){
    unsigned long long m0 = __ballot(e0 == ex);
    unsigned long long m1 = __ballot(e1 == ex);
    if (lane == 0) cnts[b * E_NUM + ex] = __popcll(m0) + __popcll(m1);
  }
}

// ---------------- scan: 1 wave; per-(block,expert) bases + fixed 264-slot sched ----------------
__global__ __launch_bounds__(64) void k_scan(const int* __restrict__ cnts,
    int* __restrict__ bases, int4* __restrict__ sched)
{
  const int lane = threadIdx.x;        // lane = g*8 + e ; 8 groups x 32 blocks
  const int e = lane & 7, g = lane >> 3;
  int own = 0;
  for (int i = 0; i < 32; ++i) own += cnts[(g * 32 + i) * E_NUM + e];
  int incl = own;
  #pragma unroll
  for (int s = 8; s < 64; s <<= 1){
    int v = __shfl_up(incl, s, 64);
    if (lane >= s) incl += v;
  }
  int tot[E_NUM];
  #pragma unroll
  for (int ee = 0; ee < E_NUM; ++ee) tot[ee] = __shfl(incl, 56 + ee, 64);
  int offs_e = 0;
  #pragma unroll
  for (int ee = 0; ee < E_NUM; ++ee) if (ee < e) offs_e += tot[ee];
  int run = offs_e + (incl - own);
  for (int i = 0; i < 32; ++i){
    const int b = g * 32 + i;
    bases[b * E_NUM + e] = run;
    run += cnts[b * E_NUM + e];
  }
  if (lane == 0){
    int slot = 0, off = 0;
    for (int ee = 0; ee < E_NUM; ++ee){
      const int c = tot[ee];
      for (int tile = 0; tile * 128 < c && slot < NTILE; ++tile)
        sched[slot++] = make_int4(ee, off + tile * 128, min(128, c - tile * 128), 0);
      off += c;
    }
    while (slot < NTILE) sched[slot++] = make_int4(0, 0, 0, 0);
  }
}

// ---------------- scatter: deterministic ballot ranks; atok = 2*t + k ----------------
__global__ __launch_bounds__(64) void k_scatter(const int* __restrict__ tki,
    const float* __restrict__ tkw, const int* __restrict__ bases,
    int* __restrict__ atok, float* __restrict__ aw)
{
  const int b = blockIdx.x, lane = threadIdx.x;
  const int t = b * 64 + lane;
  const unsigned long long lt = (1ull << lane) - 1ull;
  const int e0 = tki[2*t], e1 = tki[2*t+1];
  int r0 = 0, r1 = 0, p0c[E_NUM];
  #pragma unroll
  for (int ex = 0; ex < E_NUM; ++ex){
    unsigned long long m0 = __ballot(e0 == ex);
    p0c[ex] = __popcll(m0);
    if (e0 == ex) r0 = __popcll(m0 & lt);
  }
  #pragma unroll
  for (int ex = 0; ex < E_NUM; ++ex){
    unsigned long long m1 = __ballot(e1 == ex);
    if (e1 == ex) r1 = p0c[ex] + __popcll(m1 & lt);
  }
  const int row0 = bases[b * E_NUM + e0] + r0;
  const int row1 = bases[b * E_NUM + e1] + r1;
  atok[row0] = 2*t;     aw[row0] = tkw[2*t];
  atok[row1] = 2*t + 1; aw[row1] = tkw[2*t+1];
}

// ---------------- expert gather-GEMM: Y[2t+k] = bf16( w * (X[t] @ We[e]^T + be[e]) ) ----------------
__global__ __launch_bounds__(256) void k_expert(const unsigned short* __restrict__ Xb,
    const unsigned short* __restrict__ Web, const float* __restrict__ be,
    const int4* __restrict__ sched, const int* __restrict__ atok,
    const float* __restrict__ aw, unsigned short* __restrict__ Y)
{
  __shared__ unsigned short As[128 * 64];
  __shared__ unsigned short Bs[128 * 64];
  __shared__ int   tok_s[128];
  __shared__ float w_s[128];

  const int lin = blockIdx.x;             // [0, 2112)
  const int x = lin & 7, c = (lin >> 3) & 7, a = lin >> 6;   // a in [0,33)
  const int j = x * 33 + a;
  const int4 sc = sched[j];
  const int e = sc.x, row0 = sc.y, nval = sc.z;
  const int n0 = c * 128;

  const int tid = threadIdx.x, wv = tid >> 6, lane = tid & 63;
  const int wm = wv >> 1, wn = wv & 1, lr = lane & 15, lg = lane >> 4;

  if (tid < 128){
    tok_s[tid] = atok[row0 + max(0, min(tid, nval - 1))];
    w_s[tid]   = aw[row0 + min(tid, 127)];           // tail garbage guarded below
  }
  __syncthreads();

  const char* asrc[4]; const char* bsrc[4]; int ldso[4];
  #pragma unroll
  for (int i = 0; i < 4; ++i){
    const int chunk = i * 4 + wv;                 // 16 x 1KB
    const int byte0 = chunk * 1024 + lane * 16;
    const int r = byte0 >> 7;                     // tile row
    const int cb = byte0 & 127;
    const int scb = cb ^ ((r & 7) << 4);          // pre-swizzled source col-byte
    asrc[i] = (const char*)(Xb + (size_t)(tok_s[r] >> 1) * D_DIM) + scb;
    bsrc[i] = (const char*)(Web + ((size_t)e * D_DIM + n0 + r) * D_DIM) + scb;
    ldso[i] = chunk * 512;                        // shorts
  }

  f32x4 acc[4][4] = {};
  #pragma unroll 1
  for (int kt = 0; kt < 16; ++kt){
    __syncthreads();
    #pragma unroll
    for (int i = 0; i < 4; ++i){
      __builtin_amdgcn_global_load_lds((gas_ptr)(asrc[i] + kt * 128), (las_ptr)(As + ldso[i]), 16, 0, 0);
      __builtin_amdgcn_global_load_lds((gas_ptr)(bsrc[i] + kt * 128), (las_ptr)(Bs + ldso[i]), 16, 0, 0);
    }
    __syncthreads();
    #pragma unroll
    for (int kk = 0; kk < 2; ++kk){
      bf16x8 af[4], bfr[4];
      #pragma unroll
      for (int fm = 0; fm < 4; ++fm){
        const int r = wm*64 + fm*16 + lr;
        af[fm] = *reinterpret_cast<const bf16x8*>((char*)As + ((r*128 + kk*64 + lg*16) ^ ((r & 7) << 4)));
      }
      #pragma unroll
      for (int fn = 0; fn < 4; ++fn){
        const int r = wn*64 + fn*16 + lr;
        bfr[fn] = *reinterpret_cast<const bf16x8*>((char*)Bs + ((r*128 + kk*64 + lg*16) ^ ((r & 7) << 4)));
      }
      #pragma unroll
      for (int fm = 0; fm < 4; ++fm)
        #pragma unroll
        for (int fn = 0; fn < 4; ++fn)
          acc[fm][fn] = __builtin_amdgcn_mfma_f32_16x16x32_bf16(af[fm], bfr[fn], acc[fm][fn], 0, 0, 0);
    }
  }

  float bev[4];
  #pragma unroll
  for (int fn = 0; fn < 4; ++fn) bev[fn] = be[e * D_DIM + n0 + wn*64 + fn*16 + lr];
  #pragma unroll
  for (int fm = 0; fm < 4; ++fm){
    #pragma unroll
    for (int jj = 0; jj < 4; ++jj){
      const int r = wm*64 + fm*16 + lg*4 + jj;
      if (r < nval){
        const float w = w_s[r];
        const size_t yrow = (size_t)tok_s[r];     // 2*t + k
        #pragma unroll
        for (int fn = 0; fn < 4; ++fn){
          const int col = n0 + wn*64 + fn*16 + lr;
          Y[yrow * D_DIM + col] = f2b(w * (acc[fm][fn][jj] + bev[fn]));
        }
      }
    }
  }
}

// ---------------- out-proj: out = (Y[2t]+Y[2t+1]) @ Wo^T + bo  (dual-A MFMA, zero staging VALU) ----------------
__global__ __launch_bounds__(256) void k_outproj(const unsigned short* __restrict__ Y,
    const unsigned short* __restrict__ Wob, const float* __restrict__ bo,
    float* __restrict__ out)
{
  __shared__ unsigned short As0[128 * 64];
  __shared__ unsigned short As1[128 * 64];
  __shared__ unsigned short Bs[128 * 64];

  const int lin = blockIdx.x;             // [0, 1024)
  const int x = lin & 7, c = (lin >> 3) & 7, a = lin >> 6;   // a in [0,16)
  const int tm = x * 16 + a;
  const int n0 = c * 128;

  const int tid = threadIdx.x, wv = tid >> 6, lane = tid & 63;
  const int wm = wv >> 1, wn = wv & 1, lr = lane & 15, lg = lane >> 4;

  const char* a0src[4]; const char* a1src[4]; const char* bsrc[4]; int ldso[4];
  #pragma unroll
  for (int i = 0; i < 4; ++i){
    const int chunk = i * 4 + wv;
    const int byte0 = chunk * 1024 + lane * 16;
    const int r = byte0 >> 7;
    const int cb = byte0 & 127;
    const int scb = cb ^ ((r & 7) << 4);
    const size_t t = (size_t)(tm * 128 + r);
    a0src[i] = (const char*)(Y + (2*t)     * D_DIM) + scb;
    a1src[i] = (const char*)(Y + (2*t + 1) * D_DIM) + scb;
    bsrc[i]  = (const char*)(Wob + (size_t)(n0 + r) * D_DIM) + scb;
    ldso[i] = chunk * 512;
  }

  f32x4 acc[4][4] = {};
  #pragma unroll 1
  for (int kt = 0; kt < 16; ++kt){
    __syncthreads();
    #pragma unroll
    for (int i = 0; i < 4; ++i){
      __builtin_amdgcn_global_load_lds((gas_ptr)(a0src[i] + kt * 128), (las_ptr)(As0 + ldso[i]), 16, 0, 0);
      __builtin_amdgcn_global_load_lds((gas_ptr)(a1src[i] + kt * 128), (las_ptr)(As1 + ldso[i]), 16, 0, 0);
      __builtin_amdgcn_global_load_lds((gas_ptr)(bsrc[i] + kt * 128), (las_ptr)(Bs  + ldso[i]), 16, 0, 0);
    }
    __syncthreads();
    #pragma unroll
    for (int kk = 0; kk < 2; ++kk){
      bf16x8 a0f[4], a1f[4], bfr[4];
      #pragma unroll
      for (int fm = 0; fm < 4; ++fm){
        const int r = wm*64 + fm*16 + lr;
        const int ba = (r*128 + kk*64 + lg*16) ^ ((r & 7) << 4);
        a0f[fm] = *reinterpret_cast<const bf16x8*>((char*)As0 + ba);
        a1f[fm] = *reinterpret_cast<const bf16x8*>((char*)As1 + ba);
      }
      #pragma unroll
      for (int fn = 0; fn < 4; ++fn){
        const int r = wn*64 + fn*16 + lr;
        bfr[fn] = *reinterpret_cast<const bf16x8*>((char*)Bs + ((r*128 + kk*64 + lg*16) ^ ((r & 7) << 4)));
      }
      #pragma unroll
      for (int fm = 0; fm < 4; ++fm)
        #pragma unroll
        for (int fn = 0; fn < 4; ++fn){
          acc[fm][fn] = __builtin_amdgcn_mfma_f32_16x16x32_bf16(a0f[fm], bfr[fn], acc[fm][fn], 0, 0, 0);
          acc[fm][fn] = __builtin_amdgcn_mfma_f32_16x16x32_bf16(a1f[fm], bfr[fn], acc[fm][fn], 0, 0, 0);
        }
    }
  }

  float bov[4];
  #pragma unroll
  for (int fn = 0; fn < 4; ++fn) bov[fn] = bo[n0 + wn*64 + fn*16 + lr];
  #pragma unroll
  for (int fm = 0; fm < 4; ++fm){
    #pragma unroll
    for (int jj = 0; jj < 4; ++jj){
      const int r = wm*64 + fm*16 + lg*4 + jj;
      #pragma unroll
      for (int fn = 0; fn < 4; ++fn){
        const int col = n0 + wn*64 + fn*16 + lr;
        out[(size_t)(tm * 128 + r) * D_DIM + col] = acc[fm][fn][jj] + bov[fn];
      }
    }
  }
}

extern "C" void kernel_launch(void* const* d_in, const int* in_sizes, int n_in,
                              void* d_out, int out_size, void* d_ws, size_t ws_size,
                              hipStream_t stream)
{
  const float* X  = (const float*)d_in[0];
  const float* We = (const float*)d_in[1];
  const float* be = (const float*)d_in[2];
  const float* Wr = (const float*)d_in[3];
  const float* br = (const float*)d_in[4];
  const float* Wo = (const float*)d_in[5];
  const float* bo = (const float*)d_in[6];
  float* out = (float*)d_out;
  char* ws = (char*)d_ws;

  unsigned short* Y   = (unsigned short*)(ws + WS_Y);
  int*   atok  = (int*)(ws + WS_ATOK);
  float* aw    = (float*)(ws + WS_AW);
  int4*  sched = (int4*)(ws + WS_SCHED);
  int*   tki   = (int*)(ws + WS_TKI);
  float* tkw   = (float*)(ws + WS_TKW);
  int*   cnts  = (int*)(ws + WS_CNTS);
  int*   bases = (int*)(ws + WS_BASE);
  unsigned short* Wob = (unsigned short*)(ws + WS_WOB);

  unsigned short* Xb  = (unsigned short*)d_out;                       // 33.5 MB
  unsigned short* Web = (unsigned short*)((char*)d_out + 33554432);   // 16.8 MB (both dead before out write)

  k_router<<<T_TOK / 4, 256, 0, stream>>>(X, Wr, br, Xb, tki, tkw);
  k_cvt<<<(E_NUM * D_DIM * D_DIM / 4) / 256, 256, 0, stream>>>(We, Web, E_NUM * D_DIM * D_DIM / 4);
  k_hist<<<256, 64, 0, stream>>>(tki, cnts);
  k_scan<<<1, 64, 0, stream>>>(cnts, bases, sched);
  k_scatter<<<256, 64, 0, stream>>>(tki, tkw, bases, atok, aw);
  // Wob conversion AFTER scatter: it overwrites the tki/tkw/cnts/bases scratch region.
  k_cvt<<<(D_DIM * D_DIM / 4) / 256, 256, 0, stream>>>(Wo, Wob, D_DIM * D_DIM / 4);
  k_expert<<<NTILE * 8, 256, 0, stream>>>(Xb, Web, be, sched, atok, aw, Y);
  k_outproj<<<1024, 256, 0, stream>>>(Y, Wob, bo, out);
}

// Round 5
// 333.823 us; speedup vs baseline: 2.5797x; 1.0560x over previous
//
#include <hip/hip_runtime.h>
#include <stdint.h>

#define T_TOK 16384
#define D_DIM 1024
#define E_NUM 8
#define NTILE 136          // 256-row tiles: ceil-sum bound 135, padded

typedef __attribute__((ext_vector_type(4))) float f32x4;
typedef __attribute__((ext_vector_type(8))) __bf16 bf16x8;
typedef __attribute__((ext_vector_type(4))) unsigned short u16x4;
typedef const __attribute__((address_space(1))) void* gas_ptr;
typedef __attribute__((address_space(3))) void* las_ptr;

// ---- ws layout (ws_size >= 69,730,304 proven in round 1) ----
#define WS_Y     0ULL                      // bf16 Y[32768][1024] = 67,108,864
#define WS_ATOK  67108864ULL               // int[32768]  (value = 2*token + k)
#define WS_AW    (WS_ATOK + 131072ULL)     // float[32768]
#define WS_SCHED (WS_AW + 131072ULL)       // int4[136], padded region 8192
#define WS_TMP   (WS_SCHED + 8192ULL)      // scratch region, dead after k_scatter
#define WS_TKI   WS_TMP                    // int[2*16384]
#define WS_TKW   (WS_TKI + 131072ULL)      // float[2*16384]
#define WS_CNTS  (WS_TKW + 131072ULL)      // int[256*8]
#define WS_BASE  (WS_CNTS + 8192ULL)       // int[256*8]
#define WS_WOB   WS_TMP                    // bf16[1024][1024] (overlaps TKI.., written after scatter)

// ---- d_out layout during compute (fully overwritten by k_outproj at the end) ----
// Xb  bf16[16384][1024] at +0          (33,554,432 B)
// Web bf16[8][1024][1024] at +33554432 (16,777,216 B)

__device__ __forceinline__ unsigned short f2b(float f){
  unsigned int u = __float_as_uint(f);
  u = (u + 0x7FFFu + ((u >> 16) & 1u)) >> 16;   // RNE bf16
  return (unsigned short)u;
}

// ---------------- router: X->bf16 + logits -> top2 (by logits; softmax weights) ----------------
__global__ __launch_bounds__(256) void k_router(const float* __restrict__ X,
    const float* __restrict__ Wr, const float* __restrict__ br,
    unsigned short* __restrict__ Xb, int* __restrict__ tki, float* __restrict__ tkw)
{
  const int wv = threadIdx.x >> 6, lane = threadIdx.x & 63;
  const int t = blockIdx.x * 4 + wv;
  const float* x = X + (size_t)t * D_DIM;
  unsigned short* xb = Xb + (size_t)t * D_DIM;
  float acc[E_NUM] = {};
  #pragma unroll
  for (int c = 0; c < 4; ++c){
    const int d = c * 256 + lane * 4;
    f32x4 xv = *reinterpret_cast<const f32x4*>(x + d);
    u16x4 o;
    o[0]=f2b(xv[0]); o[1]=f2b(xv[1]); o[2]=f2b(xv[2]); o[3]=f2b(xv[3]);
    *reinterpret_cast<u16x4*>(xb + d) = o;
    #pragma unroll
    for (int e = 0; e < E_NUM; ++e){
      f32x4 w4 = *reinterpret_cast<const f32x4*>(Wr + e * D_DIM + d);
      acc[e] += xv[0]*w4[0] + xv[1]*w4[1] + xv[2]*w4[2] + xv[3]*w4[3];
    }
  }
  #pragma unroll
  for (int e = 0; e < E_NUM; ++e){
    float v = acc[e];
    #pragma unroll
    for (int off = 32; off >= 1; off >>= 1) v += __shfl_xor(v, off, 64);
    acc[e] = v + br[e];
  }
  int i1 = 0; float l1 = acc[0];
  #pragma unroll
  for (int e = 1; e < E_NUM; ++e) if (acc[e] > l1){ l1 = acc[e]; i1 = e; }
  int i2 = -1; float l2 = -3.4e38f;
  #pragma unroll
  for (int e = 0; e < E_NUM; ++e) if (e != i1 && acc[e] > l2){ l2 = acc[e]; i2 = e; }
  float s = 0.f;
  #pragma unroll
  for (int e = 0; e < E_NUM; ++e) s += __expf(acc[e] - l1);
  if (lane == 0){
    tki[2*t] = i1; tki[2*t+1] = i2;
    tkw[2*t] = 1.0f / s; tkw[2*t+1] = __expf(l2 - l1) / s;
  }
}

// ---------------- f32 -> bf16 conversion ----------------
__global__ void k_cvt(const float* __restrict__ in, unsigned short* __restrict__ out, int n4)
{
  int i = blockIdx.x * blockDim.x + threadIdx.x;
  if (i >= n4) return;
  f32x4 v = reinterpret_cast<const f32x4*>(in)[i];
  u16x4 o;
  o[0]=f2b(v[0]); o[1]=f2b(v[1]); o[2]=f2b(v[2]); o[3]=f2b(v[3]);
  reinterpret_cast<u16x4*>(out)[i] = o;
}

// ---------------- hist: per-64-token-block per-expert counts (ballot, no atomics) ----------------
__global__ __launch_bounds__(64) void k_hist(const int* __restrict__ tki, int* __restrict__ cnts)
{
  const int b = blockIdx.x, lane = threadIdx.x;
  const int t = b * 64 + lane;
  const int e0 = tki[2*t], e1 = tki[2*t+1];
  #pragma unroll
  for (int ex = 0; ex < E_NUM; ++ex){
    unsigned long long m0 = __ballot(e0 == ex);
    unsigned long long m1 = __ballot(e1 == ex);
    if (lane == 0) cnts[b * E_NUM + ex] = __popcll(m0) + __popcll(m1);
  }
}

// ---------------- scan: 1 wave; per-(block,expert) bases + fixed 136-slot sched (256-row tiles) ----------------
__global__ __launch_bounds__(64) void k_scan(const int* __restrict__ cnts,
    int* __restrict__ bases, int4* __restrict__ sched)
{
  const int lane = threadIdx.x;        // lane = g*8 + e ; 8 groups x 32 blocks
  const int e = lane & 7, g = lane >> 3;
  int own = 0;
  for (int i = 0; i < 32; ++i) own += cnts[(g * 32 + i) * E_NUM + e];
  int incl = own;
  #pragma unroll
  for (int s = 8; s < 64; s <<= 1){
    int v = __shfl_up(incl, s, 64);
    if (lane >= s) incl += v;
  }
  int tot[E_NUM];
  #pragma unroll
  for (int ee = 0; ee < E_NUM; ++ee) tot[ee] = __shfl(incl, 56 + ee, 64);
  int offs_e = 0;
  #pragma unroll
  for (int ee = 0; ee < E_NUM; ++ee) if (ee < e) offs_e += tot[ee];
  int run = offs_e + (incl - own);
  for (int i = 0; i < 32; ++i){
    const int b = g * 32 + i;
    bases[b * E_NUM + e] = run;
    run += cnts[b * E_NUM + e];
  }
  if (lane == 0){
    int slot = 0, off = 0;
    for (int ee = 0; ee < E_NUM; ++ee){
      const int c = tot[ee];
      for (int tile = 0; tile * 256 < c && slot < NTILE; ++tile)
        sched[slot++] = make_int4(ee, off + tile * 256, min(256, c - tile * 256), 0);
      off += c;
    }
    while (slot < NTILE) sched[slot++] = make_int4(0, 0, 0, 0);
  }
}

// ---------------- scatter: deterministic ballot ranks; atok = 2*t + k ----------------
__global__ __launch_bounds__(64) void k_scatter(const int* __restrict__ tki,
    const float* __restrict__ tkw, const int* __restrict__ bases,
    int* __restrict__ atok, float* __restrict__ aw)
{
  const int b = blockIdx.x, lane = threadIdx.x;
  const int t = b * 64 + lane;
  const unsigned long long lt = (1ull << lane) - 1ull;
  const int e0 = tki[2*t], e1 = tki[2*t+1];
  int r0 = 0, r1 = 0, p0c[E_NUM];
  #pragma unroll
  for (int ex = 0; ex < E_NUM; ++ex){
    unsigned long long m0 = __ballot(e0 == ex);
    p0c[ex] = __popcll(m0);
    if (e0 == ex) r0 = __popcll(m0 & lt);
  }
  #pragma unroll
  for (int ex = 0; ex < E_NUM; ++ex){
    unsigned long long m1 = __ballot(e1 == ex);
    if (e1 == ex) r1 = p0c[ex] + __popcll(m1 & lt);
  }
  const int row0 = bases[b * E_NUM + e0] + r0;
  const int row1 = bases[b * E_NUM + e1] + r1;
  atok[row0] = 2*t;     aw[row0] = tkw[2*t];
  atok[row1] = 2*t + 1; aw[row1] = tkw[2*t+1];
}

// ---------------- expert gather-GEMM, 512 thr / 8 waves, 256x128 tile ----------------
__global__ __launch_bounds__(512, 4) void k_expert(const unsigned short* __restrict__ Xb,
    const unsigned short* __restrict__ Web, const float* __restrict__ be,
    const int4* __restrict__ sched, const int* __restrict__ atok,
    const float* __restrict__ aw, unsigned short* __restrict__ Y)
{
  __shared__ unsigned short As[256 * 64];   // 32 KB
  __shared__ unsigned short Bs[128 * 64];   // 16 KB
  __shared__ int   tok_s[256];
  __shared__ float w_s[256];

  const int lin = blockIdx.x;             // [0, 1088)
  const int x = lin & 7, c = (lin >> 3) & 7, a = lin >> 6;   // a in [0,17)
  const int j = x * 17 + a;               // bijective: 136 = 8*17
  const int4 sc = sched[j];
  const int e = sc.x, row0 = sc.y, nval = sc.z;
  const int n0 = c * 128;

  const int tid = threadIdx.x, wv = tid >> 6, lane = tid & 63;
  const int wm = wv >> 1, wn = wv & 1, lr = lane & 15, lg = lane >> 4;

  if (tid < 256){
    tok_s[tid] = atok[row0 + max(0, min(tid, nval - 1))];
    w_s[tid]   = aw[row0 + min(tid, 255)];           // tail garbage guarded below
  }
  __syncthreads();

  const char* asrc[4]; const char* bsrc[2]; int ldsoA[4], ldsoB[2];
  #pragma unroll
  for (int i = 0; i < 4; ++i){
    const int chunk = i * 8 + wv;                 // 32 x 1KB (A)
    const int byte0 = chunk * 1024 + lane * 16;
    const int r = byte0 >> 7;                     // tile row [0,256)
    const int scb = (byte0 & 127) ^ ((r & 7) << 4);
    asrc[i] = (const char*)(Xb + (size_t)(tok_s[r] >> 1) * D_DIM) + scb;
    ldsoA[i] = chunk * 512;
  }
  #pragma unroll
  for (int i = 0; i < 2; ++i){
    const int chunk = i * 8 + wv;                 // 16 x 1KB (B)
    const int byte0 = chunk * 1024 + lane * 16;
    const int r = byte0 >> 7;                     // [0,128)
    const int scb = (byte0 & 127) ^ ((r & 7) << 4);
    bsrc[i] = (const char*)(Web + ((size_t)e * D_DIM + n0 + r) * D_DIM) + scb;
    ldsoB[i] = chunk * 512;
  }

  f32x4 acc[4][4] = {};
  #pragma unroll 1
  for (int kt = 0; kt < 16; ++kt){
    __syncthreads();
    #pragma unroll
    for (int i = 0; i < 4; ++i)
      __builtin_amdgcn_global_load_lds((gas_ptr)(asrc[i] + kt * 128), (las_ptr)(As + ldsoA[i]), 16, 0, 0);
    #pragma unroll
    for (int i = 0; i < 2; ++i)
      __builtin_amdgcn_global_load_lds((gas_ptr)(bsrc[i] + kt * 128), (las_ptr)(Bs + ldsoB[i]), 16, 0, 0);
    __syncthreads();
    #pragma unroll
    for (int kk = 0; kk < 2; ++kk){
      bf16x8 af[4], bfr[4];
      #pragma unroll
      for (int fm = 0; fm < 4; ++fm){
        const int r = wm*64 + fm*16 + lr;
        af[fm] = *reinterpret_cast<const bf16x8*>((char*)As + ((r*128 + kk*64 + lg*16) ^ ((r & 7) << 4)));
      }
      #pragma unroll
      for (int fn = 0; fn < 4; ++fn){
        const int r = wn*64 + fn*16 + lr;
        bfr[fn] = *reinterpret_cast<const bf16x8*>((char*)Bs + ((r*128 + kk*64 + lg*16) ^ ((r & 7) << 4)));
      }
      #pragma unroll
      for (int fm = 0; fm < 4; ++fm)
        #pragma unroll
        for (int fn = 0; fn < 4; ++fn)
          acc[fm][fn] = __builtin_amdgcn_mfma_f32_16x16x32_bf16(af[fm], bfr[fn], acc[fm][fn], 0, 0, 0);
    }
  }

  float bev[4];
  #pragma unroll
  for (int fn = 0; fn < 4; ++fn) bev[fn] = be[e * D_DIM + n0 + wn*64 + fn*16 + lr];
  #pragma unroll
  for (int fm = 0; fm < 4; ++fm){
    #pragma unroll
    for (int jj = 0; jj < 4; ++jj){
      const int r = wm*64 + fm*16 + lg*4 + jj;
      if (r < nval){
        const float w = w_s[r];
        const size_t yrow = (size_t)tok_s[r];     // 2*t + k
        #pragma unroll
        for (int fn = 0; fn < 4; ++fn){
          const int col = n0 + wn*64 + fn*16 + lr;
          Y[yrow * D_DIM + col] = f2b(w * (acc[fm][fn][jj] + bev[fn]));
        }
      }
    }
  }
}

// ---------------- out-proj, 512 thr / 8 waves, 256-token tile, dual-A MFMA ----------------
__global__ __launch_bounds__(512, 4) void k_outproj(const unsigned short* __restrict__ Y,
    const unsigned short* __restrict__ Wob, const float* __restrict__ bo,
    float* __restrict__ out)
{
  __shared__ unsigned short As0[256 * 64];  // 32 KB
  __shared__ unsigned short As1[256 * 64];  // 32 KB
  __shared__ unsigned short Bs[128 * 64];   // 16 KB

  const int lin = blockIdx.x;             // [0, 512)
  const int x = lin & 7, c = (lin >> 3) & 7, a = lin >> 6;   // a in [0,8)
  const int tm = x * 8 + a;               // bijective: 64 = 8*8
  const int n0 = c * 128;

  const int tid = threadIdx.x, wv = tid >> 6, lane = tid & 63;
  const int wm = wv >> 1, wn = wv & 1, lr = lane & 15, lg = lane >> 4;

  const char* a0src[4]; const char* a1src[4]; const char* bsrc[2]; int ldsoA[4], ldsoB[2];
  #pragma unroll
  for (int i = 0; i < 4; ++i){
    const int chunk = i * 8 + wv;
    const int byte0 = chunk * 1024 + lane * 16;
    const int r = byte0 >> 7;                     // [0,256)
    const int scb = (byte0 & 127) ^ ((r & 7) << 4);
    const size_t t = (size_t)(tm * 256 + r);
    a0src[i] = (const char*)(Y + (2*t)     * D_DIM) + scb;
    a1src[i] = (const char*)(Y + (2*t + 1) * D_DIM) + scb;
    ldsoA[i] = chunk * 512;
  }
  #pragma unroll
  for (int i = 0; i < 2; ++i){
    const int chunk = i * 8 + wv;
    const int byte0 = chunk * 1024 + lane * 16;
    const int r = byte0 >> 7;                     // [0,128)
    const int scb = (byte0 & 127) ^ ((r & 7) << 4);
    bsrc[i] = (const char*)(Wob + (size_t)(n0 + r) * D_DIM) + scb;
    ldsoB[i] = chunk * 512;
  }

  f32x4 acc[4][4] = {};
  #pragma unroll 1
  for (int kt = 0; kt < 16; ++kt){
    __syncthreads();
    #pragma unroll
    for (int i = 0; i < 4; ++i){
      __builtin_amdgcn_global_load_lds((gas_ptr)(a0src[i] + kt * 128), (las_ptr)(As0 + ldsoA[i]), 16, 0, 0);
      __builtin_amdgcn_global_load_lds((gas_ptr)(a1src[i] + kt * 128), (las_ptr)(As1 + ldsoA[i]), 16, 0, 0);
    }
    #pragma unroll
    for (int i = 0; i < 2; ++i)
      __builtin_amdgcn_global_load_lds((gas_ptr)(bsrc[i] + kt * 128), (las_ptr)(Bs + ldsoB[i]), 16, 0, 0);
    __syncthreads();
    #pragma unroll
    for (int kk = 0; kk < 2; ++kk){
      bf16x8 a0f[4], a1f[4], bfr[4];
      #pragma unroll
      for (int fm = 0; fm < 4; ++fm){
        const int r = wm*64 + fm*16 + lr;
        const int ba = (r*128 + kk*64 + lg*16) ^ ((r & 7) << 4);
        a0f[fm] = *reinterpret_cast<const bf16x8*>((char*)As0 + ba);
        a1f[fm] = *reinterpret_cast<const bf16x8*>((char*)As1 + ba);
      }
      #pragma unroll
      for (int fn = 0; fn < 4; ++fn){
        const int r = wn*64 + fn*16 + lr;
        bfr[fn] = *reinterpret_cast<const bf16x8*>((char*)Bs + ((r*128 + kk*64 + lg*16) ^ ((r & 7) << 4)));
      }
      #pragma unroll
      for (int fm = 0; fm < 4; ++fm)
        #pragma unroll
        for (int fn = 0; fn < 4; ++fn){
          acc[fm][fn] = __builtin_amdgcn_mfma_f32_16x16x32_bf16(a0f[fm], bfr[fn], acc[fm][fn], 0, 0, 0);
          acc[fm][fn] = __builtin_amdgcn_mfma_f32_16x16x32_bf16(a1f[fm], bfr[fn], acc[fm][fn], 0, 0, 0);
        }
    }
  }

  float bov[4];
  #pragma unroll
  for (int fn = 0; fn < 4; ++fn) bov[fn] = bo[n0 + wn*64 + fn*16 + lr];
  #pragma unroll
  for (int fm = 0; fm < 4; ++fm){
    #pragma unroll
    for (int jj = 0; jj < 4; ++jj){
      const int r = wm*64 + fm*16 + lg*4 + jj;
      #pragma unroll
      for (int fn = 0; fn < 4; ++fn){
        const int col = n0 + wn*64 + fn*16 + lr;
        out[(size_t)(tm * 256 + r) * D_DIM + col] = acc[fm][fn][jj] + bov[fn];
      }
    }
  }
}

extern "C" void kernel_launch(void* const* d_in, const int* in_sizes, int n_in,
                              void* d_out, int out_size, void* d_ws, size_t ws_size,
                              hipStream_t stream)
{
  const float* X  = (const float*)d_in[0];
  const float* We = (const float*)d_in[1];
  const float* be = (const float*)d_in[2];
  const float* Wr = (const float*)d_in[3];
  const float* br = (const float*)d_in[4];
  const float* Wo = (const float*)d_in[5];
  const float* bo = (const float*)d_in[6];
  float* out = (float*)d_out;
  char* ws = (char*)d_ws;

  unsigned short* Y   = (unsigned short*)(ws + WS_Y);
  int*   atok  = (int*)(ws + WS_ATOK);
  float* aw    = (float*)(ws + WS_AW);
  int4*  sched = (int4*)(ws + WS_SCHED);
  int*   tki   = (int*)(ws + WS_TKI);
  float* tkw   = (float*)(ws + WS_TKW);
  int*   cnts  = (int*)(ws + WS_CNTS);
  int*   bases = (int*)(ws + WS_BASE);
  unsigned short* Wob = (unsigned short*)(ws + WS_WOB);

  unsigned short* Xb  = (unsigned short*)d_out;                       // 33.5 MB
  unsigned short* Web = (unsigned short*)((char*)d_out + 33554432);   // 16.8 MB (both dead before out write)

  k_router<<<T_TOK / 4, 256, 0, stream>>>(X, Wr, br, Xb, tki, tkw);
  k_cvt<<<(E_NUM * D_DIM * D_DIM / 4) / 256, 256, 0, stream>>>(We, Web, E_NUM * D_DIM * D_DIM / 4);
  k_hist<<<256, 64, 0, stream>>>(tki, cnts);
  k_scan<<<1, 64, 0, stream>>>(cnts, bases, sched);
  k_scatter<<<256, 64, 0, stream>>>(tki, tkw, bases, atok, aw);
  // Wob conversion AFTER scatter: it overwrites the tki/tkw/cnts/bases scratch region.
  k_cvt<<<(D_DIM * D_DIM / 4) / 256, 256, 0, stream>>>(Wo, Wob, D_DIM * D_DIM / 4);
  k_expert<<<NTILE * 8, 512, 0, stream>>>(Xb, Web, be, sched, atok, aw, Y);
  k_outproj<<<512, 512, 0, stream>>>(Y, Wob, bo, out);
}